// Round 20
// baseline (156.461 us; speedup 1.0000x reference)
//
#include <hip/hip_runtime.h>
#include <math.h>

#define NEGM (-1e30f)

typedef __fp16 f16x4 __attribute__((ext_vector_type(4)));
typedef __fp16 f16x2 __attribute__((ext_vector_type(2)));
typedef float  f32x4 __attribute__((ext_vector_type(4)));

__device__ __forceinline__ float4 ld4(const float* p) { return *(const float4*)p; }
__device__ __forceinline__ void fma4(float4& a, float s, const float4 w) {
    a.x += s * w.x; a.y += s * w.y; a.z += s * w.z; a.w += s * w.w;
}

// ---------------- Kernel 1: hist rows + backbone-z rows in ONE launch ----------------
// Every 5th block is a z block (interleaved with hist blocks so the CU
// scheduler overlaps z's dense VALU work with hist's latency bubbles).
// hist role: 4 waves x 1 row (R18 MFMA phase code, per-wid LDS scratch).
// z role: 16 rows, x->LDS, z1->LDS, z2->global zbuf.
__global__ __launch_bounds__(256) void fused1_kernel(
    const float* __restrict__ x_kicks,
    const float* __restrict__ W_ke, const float* __restrict__ b_ke,
    const float* __restrict__ q_inner,
    const float* __restrict__ W_ge, const float* __restrict__ b_ge,
    const float* __restrict__ pos_emb, const float* __restrict__ q_outer,
    const float* __restrict__ log_temp,
    const float* __restrict__ ln_g, const float* __restrict__ ln_b,
    const int* __restrict__ outer_mask, const int* __restrict__ inner_mask,
    const float* __restrict__ x_static,
    const float* __restrict__ W1, const float* __restrict__ b1,
    const float* __restrict__ g1, const float* __restrict__ be1,
    const float* __restrict__ m1, const float* __restrict__ v1,
    const float* __restrict__ W2, const float* __restrict__ b2,
    const float* __restrict__ g2, const float* __restrict__ be2,
    const float* __restrict__ m2, const float* __restrict__ v2,
    float* __restrict__ hist, float* __restrict__ zbuf)
{
    __shared__ float smem[5200];
    const int tid = threadIdx.x;
    const int q5 = blockIdx.x / 5;
    const int r5 = blockIdx.x - q5 * 5;

    if (r5 < 4) {
        // ================= hist role =================
        const int hb   = q5 * 4 + r5;        // 0..4095
        const int wid  = tid >> 6;
        const int lane = tid & 63;
        const int b    = hb * 4 + wid;       // batch row
        const int jcol = lane & 15;
        const int g    = lane >> 4;
        const int kb   = g * 4;

        float* s_wge  = smem;                // 512
        float* s_qout = smem + 512;          // 256
        float* scr = smem + 768 + wid * 1108;
        float* pg  = scr;                    // 340
        float* enc = scr + 340;              // 612
        float* ao  = scr + 952;              // 136
        float* sS  = scr + 1088;             // 20

        s_wge[tid] = W_ge[tid];
        s_wge[tid + 256] = W_ge[tid + 256];
        s_qout[tid] = q_outer[tid];
        __syncthreads();

        f16x4 bw;
        #pragma unroll
        for (int jj = 0; jj < 4; ++jj)
            bw[jj] = (__fp16)W_ke[(kb + jj) * 16 + jcol];
        const float bias = b_ke[jcol];
        const f32x4 cinit = {bias, bias, bias, bias};
        const float qv = q_inner[jcol] * 0.25f;

        const float* xb = x_kicks + (size_t)b * 204 * 16;
        const int*   mb = inner_mask + (size_t)b * 204;

        f32x4 PG   = {0.f, 0.f, 0.f, 0.f};
        f32x4 PG16 = {0.f, 0.f, 0.f, 0.f};
        float Sacc = 0.f, S16 = 0.f;

        int g0 = (g == 3) ? 1 : 0;
        int p0 = (g == 3) ? 0 : 4 * g;

        #pragma unroll
        for (int t = 0; t < 12; ++t) {
            float4 xv = ld4(xb + (16 * t + jcol) * 16 + kb);
            int4 mv = *(const int4*)(mb + 16 * t + 4 * g);

            f16x2 xlo = __builtin_amdgcn_cvt_pkrtz(xv.x, xv.y);
            f16x2 xhi = __builtin_amdgcn_cvt_pkrtz(xv.z, xv.w);
            f16x4 ax; ax[0]=xlo[0]; ax[1]=xlo[1]; ax[2]=xhi[0]; ax[3]=xhi[1];

            f32x4 D1 = __builtin_amdgcn_mfma_f32_16x16x16f16(ax, bw, cinit, 0, 0, 0);
            #pragma unroll
            for (int jj = 0; jj < 4; ++jj) D1[jj] = fmaxf(D1[jj], 0.f);

            f16x2 pA = __builtin_amdgcn_cvt_pkrtz(D1[0] * qv, D1[1] * qv);
            f16x2 pB = __builtin_amdgcn_cvt_pkrtz(D1[2] * qv, D1[3] * qv);
            #pragma unroll
            for (int o = 1; o < 16; o <<= 1) {
                int ia = __shfl_xor(__builtin_bit_cast(int, pA), o);
                int ib = __shfl_xor(__builtin_bit_cast(int, pB), o);
                pA = pA + __builtin_bit_cast(f16x2, ia);
                pB = pB + __builtin_bit_cast(f16x2, ib);
            }
            float s0 = (float)pA[0], s1 = (float)pA[1];
            float s2 = (float)pB[0], s3 = (float)pB[1];

            f16x4 aw;
            #pragma unroll
            for (int jj = 0; jj < 4; ++jj) {
                int mk = (jj==0)?mv.x:(jj==1)?mv.y:(jj==2)?mv.z:mv.w;
                float sv = (jj==0)?s0:(jj==1)?s1:(jj==2)?s2:s3;
                float e = mk ? __expf(sv) : 0.f;
                int game_jj = g0 + ((p0 + jj) >= 12 ? 1 : 0);
                float w = (game_jj == jcol) ? e : 0.f;
                aw[jj] = (__fp16)w;
                Sacc += w;
            }
            g0 += 1; p0 += 4;
            if (p0 >= 12) { p0 -= 12; g0 += 1; }

            f16x2 elo = __builtin_amdgcn_cvt_pkrtz(D1[0], D1[1]);
            f16x2 ehi = __builtin_amdgcn_cvt_pkrtz(D1[2], D1[3]);
            f16x4 be; be[0]=elo[0]; be[1]=elo[1]; be[2]=ehi[0]; be[3]=ehi[1];

            PG = __builtin_amdgcn_mfma_f32_16x16x16f16(aw, be, PG, 0, 0, 0);
        }

        {   // tile 12 : game 16
            int kidx = 192 + jcol;
            int kc = (kidx < 204) ? kidx : 203;
            float4 xv = ld4(xb + kc * 16 + kb);
            int km = 192 + 4 * g;
            int kmc = (km <= 200) ? km : 200;
            int4 mv = *(const int4*)(mb + kmc);

            f16x2 xlo = __builtin_amdgcn_cvt_pkrtz(xv.x, xv.y);
            f16x2 xhi = __builtin_amdgcn_cvt_pkrtz(xv.z, xv.w);
            f16x4 ax; ax[0]=xlo[0]; ax[1]=xlo[1]; ax[2]=xhi[0]; ax[3]=xhi[1];

            f32x4 D1 = __builtin_amdgcn_mfma_f32_16x16x16f16(ax, bw, cinit, 0, 0, 0);
            #pragma unroll
            for (int jj = 0; jj < 4; ++jj) D1[jj] = fmaxf(D1[jj], 0.f);

            f16x2 pA = __builtin_amdgcn_cvt_pkrtz(D1[0] * qv, D1[1] * qv);
            f16x2 pB = __builtin_amdgcn_cvt_pkrtz(D1[2] * qv, D1[3] * qv);
            #pragma unroll
            for (int o = 1; o < 16; o <<= 1) {
                int ia = __shfl_xor(__builtin_bit_cast(int, pA), o);
                int ib = __shfl_xor(__builtin_bit_cast(int, pB), o);
                pA = pA + __builtin_bit_cast(f16x2, ia);
                pB = pB + __builtin_bit_cast(f16x2, ib);
            }
            float s0 = (float)pA[0], s1 = (float)pA[1];
            float s2 = (float)pB[0], s3 = (float)pB[1];

            f16x4 aw2;
            #pragma unroll
            for (int jj = 0; jj < 4; ++jj) {
                int pos = 4 * g + jj;
                int mk = (jj==0)?mv.x:(jj==1)?mv.y:(jj==2)?mv.z:mv.w;
                float sv = (jj==0)?s0:(jj==1)?s1:(jj==2)?s2:s3;
                bool valid = (pos < 12) && mk;
                float e = valid ? __expf(sv) : 0.f;
                float w = (jcol == 0) ? e : 0.f;
                aw2[jj] = (__fp16)w;
                S16 += w;
            }

            f16x2 elo = __builtin_amdgcn_cvt_pkrtz(D1[0], D1[1]);
            f16x2 ehi = __builtin_amdgcn_cvt_pkrtz(D1[2], D1[3]);
            f16x4 be; be[0]=elo[0]; be[1]=elo[1]; be[2]=ehi[0]; be[3]=ehi[1];

            PG16 = __builtin_amdgcn_mfma_f32_16x16x16f16(aw2, be, PG16, 0, 0, 0);
        }

        Sacc += __shfl_xor(Sacc, 16);
        Sacc += __shfl_xor(Sacc, 32);
        S16 += __shfl_xor(S16, 16);
        S16 += __shfl_xor(S16, 32);

        if (lane < 16) sS[lane] = Sacc;
        if (lane == 0) sS[16] = S16;
        __syncthreads();

        #pragma unroll
        for (int jj = 0; jj < 4; ++jj) {
            int game = kb + jj;
            pg[game * 20 + jcol] = PG[jj] * (1.f / sS[game]);
        }
        if (lane < 16) pg[16 * 20 + lane] = PG16[0] * (1.f / sS[16]);
        __syncthreads();

        // Phase B
        for (int t = lane; t < 136; t += 64) {
            const int gg = t >> 3, dq = t & 7;
            float4 acc = ld4(b_ge + dq * 4);
            #pragma unroll
            for (int i = 0; i < 16; ++i) {
                float pv = pg[gg * 20 + i];
                fma4(acc, pv, *(float4*)&s_wge[i * 32 + dq * 4]);
            }
            float4 pe = ld4(pos_emb + gg * 32 + dq * 4);
            acc.x = fmaxf(acc.x, 0.f) + pe.x; acc.y = fmaxf(acc.y, 0.f) + pe.y;
            acc.z = fmaxf(acc.z, 0.f) + pe.z; acc.w = fmaxf(acc.w, 0.f) + pe.w;
            *(float4*)&enc[gg * 36 + dq * 4] = acc;
        }
        __syncthreads();

        // Phase C
        for (int t = lane; t < 136; t += 64) {
            const int q = t / 17, gg = t - q * 17;
            float4 acc = {0.f, 0.f, 0.f, 0.f};
            #pragma unroll
            for (int i4 = 0; i4 < 8; ++i4) {
                float4 ev = *(float4*)&enc[gg * 36 + i4 * 4];
                float4 qvv = *(float4*)&s_qout[q * 32 + i4 * 4];
                acc.x += ev.x * qvv.x; acc.y += ev.y * qvv.y;
                acc.z += ev.z * qvv.z; acc.w += ev.w * qvv.w;
            }
            float sv = (acc.x + acc.y) + (acc.z + acc.w);
            sv *= 0.17677669529663687f * __expf(-log_temp[q >> 1]);
            ao[t] = outer_mask[b * 17 + gg] ? sv : NEGM;
        }
        __syncthreads();

        // Phase D
        {
            const int q = lane >> 3, j = lane & 7;
            float s0 = ao[q * 17 + j];
            float s1 = ao[q * 17 + j + 8];
            float s2 = (j == 0) ? ao[q * 17 + 16] : NEGM;
            float mx = fmaxf(fmaxf(s0, s1), s2);
            mx = fmaxf(mx, __shfl_xor(mx, 1));
            mx = fmaxf(mx, __shfl_xor(mx, 2));
            mx = fmaxf(mx, __shfl_xor(mx, 4));
            float e0 = __expf(s0 - mx), e1 = __expf(s1 - mx);
            float e2 = (j == 0) ? __expf(s2 - mx) : 0.f;
            float ssum = e0 + e1 + e2;
            ssum += __shfl_xor(ssum, 1);
            ssum += __shfl_xor(ssum, 2);
            ssum += __shfl_xor(ssum, 4);
            float inv = 1.f / ssum;
            ao[q * 17 + j] = e0 * inv;
            ao[q * 17 + j + 8] = e1 * inv;
            if (j == 0) ao[q * 17 + 16] = e2 * inv;
        }
        __syncthreads();

        // Phase E
        {
            const int q = lane >> 3, dq = lane & 7;
            float4 acc = {0.f, 0.f, 0.f, 0.f};
            #pragma unroll
            for (int gg = 0; gg < 17; ++gg) {
                float w = ao[q * 17 + gg];
                fma4(acc, w, *(float4*)&enc[gg * 36 + dq * 4]);
            }
            float sv = (acc.x + acc.y) + (acc.z + acc.w);
            sv += __shfl_xor(sv, 1); sv += __shfl_xor(sv, 2);
            sv += __shfl_xor(sv, 4); sv += __shfl_xor(sv, 8);
            float mu = sv * 0.015625f;
            float4 d;
            d.x = acc.x - mu; d.y = acc.y - mu; d.z = acc.z - mu; d.w = acc.w - mu;
            float v = (d.x * d.x + d.y * d.y) + (d.z * d.z + d.w * d.w);
            v += __shfl_xor(v, 1); v += __shfl_xor(v, 2);
            v += __shfl_xor(v, 4); v += __shfl_xor(v, 8);
            float rs = rsqrtf(v * 0.015625f + 1e-5f);
            float4 gam = ld4(ln_g + lane * 4);
            float4 bet = ld4(ln_b + lane * 4);
            float4 res;
            res.x = d.x * rs * gam.x + bet.x; res.y = d.y * rs * gam.y + bet.y;
            res.z = d.z * rs * gam.z + bet.z; res.w = d.w * rs * gam.w + bet.w;
            *(float4*)&hist[(size_t)b * 256 + lane * 4] = res;
        }
    } else {
        // ================= z role: 16 rows, z1->LDS, z2->global =================
        const int row0 = q5 * 16;
        float* s_x  = smem;          // 1024
        float* s_z1 = smem + 1024;   // 4096

        *(float4*)&s_x[tid * 4] = ld4(x_static + (size_t)row0 * 64 + tid * 4);
        __syncthreads();

        {
            const int col = tid;
            float acc[16];
            #pragma unroll
            for (int r = 0; r < 16; ++r) acc[r] = 0.f;
            for (int k4 = 0; k4 < 16; ++k4) {
                float w0 = W1[(k4 * 4 + 0) * 256 + col];
                float w1 = W1[(k4 * 4 + 1) * 256 + col];
                float w2 = W1[(k4 * 4 + 2) * 256 + col];
                float w3 = W1[(k4 * 4 + 3) * 256 + col];
                #pragma unroll
                for (int r = 0; r < 16; ++r) {
                    float4 xv = *(float4*)&s_x[r * 64 + k4 * 4];
                    acc[r] += xv.x * w0 + xv.y * w1 + xv.z * w2 + xv.w * w3;
                }
            }
            float sc = rsqrtf(v1[col] + 1e-5f) * g1[col];
            float off = b1[col] - m1[col];
            float bb = be1[col];
            #pragma unroll
            for (int r = 0; r < 16; ++r)
                s_z1[r * 256 + col] = fmaxf((acc[r] + off) * sc + bb, 0.f);
        }
        __syncthreads();

        {
            const int col = tid & 127;
            const int r0 = (tid >> 7) * 8;
            float acc[8];
            #pragma unroll
            for (int r = 0; r < 8; ++r) acc[r] = 0.f;
            for (int k4 = 0; k4 < 64; ++k4) {
                float w0 = W2[(k4 * 4 + 0) * 128 + col];
                float w1 = W2[(k4 * 4 + 1) * 128 + col];
                float w2 = W2[(k4 * 4 + 2) * 128 + col];
                float w3 = W2[(k4 * 4 + 3) * 128 + col];
                #pragma unroll
                for (int r = 0; r < 8; ++r) {
                    float4 zv = *(float4*)&s_z1[(r0 + r) * 256 + k4 * 4];
                    acc[r] += zv.x * w0 + zv.y * w1 + zv.z * w2 + zv.w * w3;
                }
            }
            float sc = rsqrtf(v2[col] + 1e-5f) * g2[col];
            float off = b2[col] - m2[col];
            float bb = be2[col];
            #pragma unroll
            for (int r = 0; r < 8; ++r)
                zbuf[(size_t)(row0 + r0 + r) * 128 + col] =
                    fmaxf((acc[r] + off) * sc + bb, 0.f);
        }
    }
}

// ---------------- Kernel 2: per-target heads ----------------
// 16 rows per block. Stages z2 tile to LDS (132-stride), heads code as before.
__global__ __launch_bounds__(256) void heads_kernel(
    const float* __restrict__ zbuf, const float* __restrict__ hist,
    const float* __restrict__ Wh1, const float* __restrict__ bh1,
    const float* __restrict__ Wh2, const float* __restrict__ bh2,
    float* __restrict__ out)
{
    __shared__ float s_z2[16 * 132];
    const int tid = threadIdx.x;
    const int row0 = blockIdx.x * 16;

    {
        const int r = tid >> 4, c = (tid & 15) * 8;
        float4 v0 = ld4(zbuf + (size_t)(row0 + r) * 128 + c);
        float4 v1 = ld4(zbuf + (size_t)(row0 + r) * 128 + c + 4);
        *(float4*)&s_z2[r * 132 + c] = v0;
        *(float4*)&s_z2[r * 132 + c + 4] = v1;
    }
    __syncthreads();

    const int p = tid >> 2;
    const int gl = tid & 3;
    const int row = p >> 2;
    const int tgt = p & 3;
    const int j0 = gl * 8;

    float acc[8];
    #pragma unroll
    for (int j = 0; j < 8; ++j) acc[j] = bh1[tgt * 32 + j0 + j];

    const float* w1p = Wh1 + (size_t)tgt * 192 * 32 + j0;
    for (int d4 = 0; d4 < 32; ++d4) {
        float4 zv = *(float4*)&s_z2[row * 132 + d4 * 4];
        #pragma unroll
        for (int c = 0; c < 4; ++c) {
            float v = (c == 0) ? zv.x : (c == 1) ? zv.y : (c == 2) ? zv.z : zv.w;
            float4 a = ld4(w1p + (d4 * 4 + c) * 32);
            float4 bq = ld4(w1p + (d4 * 4 + c) * 32 + 4);
            acc[0] += v * a.x;  acc[1] += v * a.y;  acc[2] += v * a.z;  acc[3] += v * a.w;
            acc[4] += v * bq.x; acc[5] += v * bq.y; acc[6] += v * bq.z; acc[7] += v * bq.w;
        }
    }
    const float* hp = hist + (size_t)(row0 + row) * 256 + tgt * 64;
    const float* w1q = w1p + 128 * 32;
    for (int d4 = 0; d4 < 16; ++d4) {
        float4 hv = ld4(hp + d4 * 4);
        #pragma unroll
        for (int c = 0; c < 4; ++c) {
            float v = (c == 0) ? hv.x : (c == 1) ? hv.y : (c == 2) ? hv.z : hv.w;
            float4 a = ld4(w1q + (d4 * 4 + c) * 32);
            float4 bq = ld4(w1q + (d4 * 4 + c) * 32 + 4);
            acc[0] += v * a.x;  acc[1] += v * a.y;  acc[2] += v * a.z;  acc[3] += v * a.w;
            acc[4] += v * bq.x; acc[5] += v * bq.y; acc[6] += v * bq.z; acc[7] += v * bq.w;
        }
    }
    float ps = 0.f;
    #pragma unroll
    for (int j = 0; j < 8; ++j) ps += fmaxf(acc[j], 0.f) * Wh2[tgt * 32 + j0 + j];
    ps += __shfl_xor(ps, 1);
    ps += __shfl_xor(ps, 2);
    if (gl == 0) out[(size_t)(row0 + row) * 4 + tgt] = fmaxf(ps + bh2[tgt], 0.f);
}

extern "C" void kernel_launch(void* const* d_in, const int* in_sizes, int n_in,
                              void* d_out, int out_size, void* d_ws, size_t ws_size,
                              hipStream_t stream) {
    const float* x_static = (const float*)d_in[0];
    const float* x_kicks  = (const float*)d_in[1];
    const float* W_ke     = (const float*)d_in[2];
    const float* b_ke     = (const float*)d_in[3];
    const float* q_inner  = (const float*)d_in[4];
    const float* W_ge     = (const float*)d_in[5];
    const float* b_ge     = (const float*)d_in[6];
    const float* pos_emb  = (const float*)d_in[7];
    const float* q_outer  = (const float*)d_in[8];
    const float* log_temp = (const float*)d_in[9];
    const float* ln_g     = (const float*)d_in[10];
    const float* ln_b     = (const float*)d_in[11];
    const float* W1       = (const float*)d_in[12];
    const float* b1       = (const float*)d_in[13];
    const float* g1       = (const float*)d_in[14];
    const float* be1      = (const float*)d_in[15];
    const float* m1       = (const float*)d_in[16];
    const float* v1       = (const float*)d_in[17];
    const float* W2       = (const float*)d_in[18];
    const float* b2       = (const float*)d_in[19];
    const float* g2       = (const float*)d_in[20];
    const float* be2      = (const float*)d_in[21];
    const float* m2       = (const float*)d_in[22];
    const float* v2       = (const float*)d_in[23];
    const float* Wh1      = (const float*)d_in[24];
    const float* bh1      = (const float*)d_in[25];
    const float* Wh2      = (const float*)d_in[26];
    const float* bh2      = (const float*)d_in[27];
    const int* outer_mask = (const int*)d_in[28];
    const int* inner_mask = (const int*)d_in[29];

    float* hist = (float*)d_ws;                        // 16384*256 floats = 16.8 MB
    float* zbuf = hist + (size_t)16384 * 256;          // 16384*128 floats =  8.4 MB
    float* out  = (float*)d_out;

    fused1_kernel<<<5120, 256, 0, stream>>>(
        x_kicks, W_ke, b_ke, q_inner, W_ge, b_ge, pos_emb, q_outer,
        log_temp, ln_g, ln_b, outer_mask, inner_mask,
        x_static, W1, b1, g1, be1, m1, v1, W2, b2, g2, be2, m2, v2,
        hist, zbuf);

    heads_kernel<<<1024, 256, 0, stream>>>(
        zbuf, hist, Wh1, bh1, Wh2, bh2, out);
}

// Round 21
// 144.219 us; speedup vs baseline: 1.0849x; 1.0849x over previous
//
#include <hip/hip_runtime.h>
#include <math.h>

#define NEGM (-1e30f)

typedef __fp16 f16x4 __attribute__((ext_vector_type(4)));
typedef __fp16 f16x2 __attribute__((ext_vector_type(2)));
typedef float  f32x4 __attribute__((ext_vector_type(4)));

__device__ __forceinline__ float4 ld4(const float* p) { return *(const float4*)p; }
__device__ __forceinline__ void fma4(float4& a, float s, const float4 w) {
    a.x += s * w.x; a.y += s * w.y; a.z += s * w.z; a.w += s * w.w;
}

// ---------------- Kernel 1: nested-attention history path ----------------
// R18 wave code, packed 4 rows per 256-thread block (per-wid LDS scratch):
// 20.8 KB LDS -> 7 blocks x 4 waves = 28 waves/CU potential, vs the 1-wave
// workgroup residency band (~16-19). Single variable: WG residency.
__global__ __launch_bounds__(256) void hist_kernel(
    const float* __restrict__ x_kicks,
    const float* __restrict__ W_ke, const float* __restrict__ b_ke,
    const float* __restrict__ q_inner,
    const float* __restrict__ W_ge, const float* __restrict__ b_ge,
    const float* __restrict__ pos_emb, const float* __restrict__ q_outer,
    const float* __restrict__ log_temp,
    const float* __restrict__ ln_g, const float* __restrict__ ln_b,
    const int* __restrict__ outer_mask, const int* __restrict__ inner_mask,
    float* __restrict__ hist)
{
    __shared__ float smem[5200];
    const int tid  = threadIdx.x;
    const int wid  = tid >> 6;
    const int lane = tid & 63;
    const int b    = blockIdx.x * 4 + wid;
    const int jcol = lane & 15;
    const int g    = lane >> 4;
    const int kb   = g * 4;

    float* s_wge  = smem;                // 512
    float* s_qout = smem + 512;          // 256
    float* scr = smem + 768 + wid * 1108;
    float* pg  = scr;                    // 340 (17*20)
    float* enc = scr + 340;              // 612 (17*36)
    float* ao  = scr + 952;              // 136
    float* sS  = scr + 1088;             // 20

    s_wge[tid] = W_ge[tid];
    s_wge[tid + 256] = W_ge[tid + 256];
    s_qout[tid] = q_outer[tid];
    __syncthreads();

    f16x4 bw;
    #pragma unroll
    for (int jj = 0; jj < 4; ++jj)
        bw[jj] = (__fp16)W_ke[(kb + jj) * 16 + jcol];
    const float bias = b_ke[jcol];
    const f32x4 cinit = {bias, bias, bias, bias};
    const float qv = q_inner[jcol] * 0.25f;

    const float* xb = x_kicks + (size_t)b * 204 * 16;
    const int*   mb = inner_mask + (size_t)b * 204;

    f32x4 PG   = {0.f, 0.f, 0.f, 0.f};
    f32x4 PG16 = {0.f, 0.f, 0.f, 0.f};
    float Sacc = 0.f, S16 = 0.f;

    int g0 = (g == 3) ? 1 : 0;
    int p0 = (g == 3) ? 0 : 4 * g;

    // ---------- tiles 0..11 : games 0..15 ----------
    #pragma unroll
    for (int t = 0; t < 12; ++t) {
        float4 xv = ld4(xb + (16 * t + jcol) * 16 + kb);
        int4 mv = *(const int4*)(mb + 16 * t + 4 * g);

        f16x2 xlo = __builtin_amdgcn_cvt_pkrtz(xv.x, xv.y);
        f16x2 xhi = __builtin_amdgcn_cvt_pkrtz(xv.z, xv.w);
        f16x4 ax; ax[0]=xlo[0]; ax[1]=xlo[1]; ax[2]=xhi[0]; ax[3]=xhi[1];

        f32x4 D1 = __builtin_amdgcn_mfma_f32_16x16x16f16(ax, bw, cinit, 0, 0, 0);
        #pragma unroll
        for (int jj = 0; jj < 4; ++jj) D1[jj] = fmaxf(D1[jj], 0.f);

        f16x2 pA = __builtin_amdgcn_cvt_pkrtz(D1[0] * qv, D1[1] * qv);
        f16x2 pB = __builtin_amdgcn_cvt_pkrtz(D1[2] * qv, D1[3] * qv);
        #pragma unroll
        for (int o = 1; o < 16; o <<= 1) {
            int ia = __shfl_xor(__builtin_bit_cast(int, pA), o);
            int ib = __shfl_xor(__builtin_bit_cast(int, pB), o);
            pA = pA + __builtin_bit_cast(f16x2, ia);
            pB = pB + __builtin_bit_cast(f16x2, ib);
        }
        float s0 = (float)pA[0], s1 = (float)pA[1];
        float s2 = (float)pB[0], s3 = (float)pB[1];

        f16x4 aw;
        #pragma unroll
        for (int jj = 0; jj < 4; ++jj) {
            int mk = (jj==0)?mv.x:(jj==1)?mv.y:(jj==2)?mv.z:mv.w;
            float sv = (jj==0)?s0:(jj==1)?s1:(jj==2)?s2:s3;
            float e = mk ? __expf(sv) : 0.f;
            int game_jj = g0 + ((p0 + jj) >= 12 ? 1 : 0);
            float w = (game_jj == jcol) ? e : 0.f;
            aw[jj] = (__fp16)w;
            Sacc += w;
        }
        g0 += 1; p0 += 4;
        if (p0 >= 12) { p0 -= 12; g0 += 1; }

        f16x2 elo = __builtin_amdgcn_cvt_pkrtz(D1[0], D1[1]);
        f16x2 ehi = __builtin_amdgcn_cvt_pkrtz(D1[2], D1[3]);
        f16x4 be; be[0]=elo[0]; be[1]=elo[1]; be[2]=ehi[0]; be[3]=ehi[1];

        PG = __builtin_amdgcn_mfma_f32_16x16x16f16(aw, be, PG, 0, 0, 0);
    }

    // ---------- tile 12 : game 16 (kicks 192..203) ----------
    {
        int kidx = 192 + jcol;
        int kc = (kidx < 204) ? kidx : 203;
        float4 xv = ld4(xb + kc * 16 + kb);
        int km = 192 + 4 * g;
        int kmc = (km <= 200) ? km : 200;
        int4 mv = *(const int4*)(mb + kmc);

        f16x2 xlo = __builtin_amdgcn_cvt_pkrtz(xv.x, xv.y);
        f16x2 xhi = __builtin_amdgcn_cvt_pkrtz(xv.z, xv.w);
        f16x4 ax; ax[0]=xlo[0]; ax[1]=xlo[1]; ax[2]=xhi[0]; ax[3]=xhi[1];

        f32x4 D1 = __builtin_amdgcn_mfma_f32_16x16x16f16(ax, bw, cinit, 0, 0, 0);
        #pragma unroll
        for (int jj = 0; jj < 4; ++jj) D1[jj] = fmaxf(D1[jj], 0.f);

        f16x2 pA = __builtin_amdgcn_cvt_pkrtz(D1[0] * qv, D1[1] * qv);
        f16x2 pB = __builtin_amdgcn_cvt_pkrtz(D1[2] * qv, D1[3] * qv);
        #pragma unroll
        for (int o = 1; o < 16; o <<= 1) {
            int ia = __shfl_xor(__builtin_bit_cast(int, pA), o);
            int ib = __shfl_xor(__builtin_bit_cast(int, pB), o);
            pA = pA + __builtin_bit_cast(f16x2, ia);
            pB = pB + __builtin_bit_cast(f16x2, ib);
        }
        float s0 = (float)pA[0], s1 = (float)pA[1];
        float s2 = (float)pB[0], s3 = (float)pB[1];

        f16x4 aw2;
        #pragma unroll
        for (int jj = 0; jj < 4; ++jj) {
            int pos = 4 * g + jj;
            int mk = (jj==0)?mv.x:(jj==1)?mv.y:(jj==2)?mv.z:mv.w;
            float sv = (jj==0)?s0:(jj==1)?s1:(jj==2)?s2:s3;
            bool valid = (pos < 12) && mk;
            float e = valid ? __expf(sv) : 0.f;
            float w = (jcol == 0) ? e : 0.f;
            aw2[jj] = (__fp16)w;
            S16 += w;
        }

        f16x2 elo = __builtin_amdgcn_cvt_pkrtz(D1[0], D1[1]);
        f16x2 ehi = __builtin_amdgcn_cvt_pkrtz(D1[2], D1[3]);
        f16x4 be; be[0]=elo[0]; be[1]=elo[1]; be[2]=ehi[0]; be[3]=ehi[1];

        PG16 = __builtin_amdgcn_mfma_f32_16x16x16f16(aw2, be, PG16, 0, 0, 0);
    }

    // ---------- denominators & per_game write ----------
    Sacc += __shfl_xor(Sacc, 16);
    Sacc += __shfl_xor(Sacc, 32);
    S16 += __shfl_xor(S16, 16);
    S16 += __shfl_xor(S16, 32);

    if (lane < 16) sS[lane] = Sacc;
    if (lane == 0) sS[16] = S16;
    __syncthreads();

    #pragma unroll
    for (int jj = 0; jj < 4; ++jj) {
        int game = kb + jj;
        pg[game * 20 + jcol] = PG[jj] * (1.f / sS[game]);
    }
    if (lane < 16) pg[16 * 20 + lane] = PG16[0] * (1.f / sS[16]);
    __syncthreads();

    // ---------- Phase B: game encoder + pos emb -> enc[17][32] ----------
    for (int t = lane; t < 136; t += 64) {
        const int gg = t >> 3, dq = t & 7;
        float4 acc = ld4(b_ge + dq * 4);
        #pragma unroll
        for (int i = 0; i < 16; ++i) {
            float pv = pg[gg * 20 + i];
            fma4(acc, pv, *(float4*)&s_wge[i * 32 + dq * 4]);
        }
        float4 pe = ld4(pos_emb + gg * 32 + dq * 4);
        acc.x = fmaxf(acc.x, 0.f) + pe.x; acc.y = fmaxf(acc.y, 0.f) + pe.y;
        acc.z = fmaxf(acc.z, 0.f) + pe.z; acc.w = fmaxf(acc.w, 0.f) + pe.w;
        *(float4*)&enc[gg * 36 + dq * 4] = acc;
    }
    __syncthreads();

    // ---------- Phase C: outer attention scores ao[8][17] ----------
    for (int t = lane; t < 136; t += 64) {
        const int q = t / 17, gg = t - q * 17;
        float4 acc = {0.f, 0.f, 0.f, 0.f};
        #pragma unroll
        for (int i4 = 0; i4 < 8; ++i4) {
            float4 ev = *(float4*)&enc[gg * 36 + i4 * 4];
            float4 qvv = *(float4*)&s_qout[q * 32 + i4 * 4];
            acc.x += ev.x * qvv.x; acc.y += ev.y * qvv.y;
            acc.z += ev.z * qvv.z; acc.w += ev.w * qvv.w;
        }
        float sv = (acc.x + acc.y) + (acc.z + acc.w);
        sv *= 0.17677669529663687f * __expf(-log_temp[q >> 1]);
        ao[t] = outer_mask[b * 17 + gg] ? sv : NEGM;
    }
    __syncthreads();

    // ---------- Phase D: outer softmax (8 lanes per query) ----------
    {
        const int q = lane >> 3, j = lane & 7;
        float s0 = ao[q * 17 + j];
        float s1 = ao[q * 17 + j + 8];
        float s2 = (j == 0) ? ao[q * 17 + 16] : NEGM;
        float mx = fmaxf(fmaxf(s0, s1), s2);
        mx = fmaxf(mx, __shfl_xor(mx, 1));
        mx = fmaxf(mx, __shfl_xor(mx, 2));
        mx = fmaxf(mx, __shfl_xor(mx, 4));
        float e0 = __expf(s0 - mx), e1 = __expf(s1 - mx);
        float e2 = (j == 0) ? __expf(s2 - mx) : 0.f;
        float ssum = e0 + e1 + e2;
        ssum += __shfl_xor(ssum, 1);
        ssum += __shfl_xor(ssum, 2);
        ssum += __shfl_xor(ssum, 4);
        float inv = 1.f / ssum;
        ao[q * 17 + j] = e0 * inv;
        ao[q * 17 + j + 8] = e1 * inv;
        if (j == 0) ao[q * 17 + 16] = e2 * inv;
    }
    __syncthreads();

    // ---------- Phase E: pooled + per-target LayerNorm ----------
    {
        const int q = lane >> 3, dq = lane & 7;
        float4 acc = {0.f, 0.f, 0.f, 0.f};
        #pragma unroll
        for (int gg = 0; gg < 17; ++gg) {
            float w = ao[q * 17 + gg];
            fma4(acc, w, *(float4*)&enc[gg * 36 + dq * 4]);
        }
        float sv = (acc.x + acc.y) + (acc.z + acc.w);
        sv += __shfl_xor(sv, 1); sv += __shfl_xor(sv, 2);
        sv += __shfl_xor(sv, 4); sv += __shfl_xor(sv, 8);
        float mu = sv * 0.015625f;
        float4 d;
        d.x = acc.x - mu; d.y = acc.y - mu; d.z = acc.z - mu; d.w = acc.w - mu;
        float v = (d.x * d.x + d.y * d.y) + (d.z * d.z + d.w * d.w);
        v += __shfl_xor(v, 1); v += __shfl_xor(v, 2);
        v += __shfl_xor(v, 4); v += __shfl_xor(v, 8);
        float rs = rsqrtf(v * 0.015625f + 1e-5f);
        float4 gam = ld4(ln_g + lane * 4);
        float4 bet = ld4(ln_b + lane * 4);
        float4 res;
        res.x = d.x * rs * gam.x + bet.x; res.y = d.y * rs * gam.y + bet.y;
        res.z = d.z * rs * gam.z + bet.z; res.w = d.w * rs * gam.w + bet.w;
        *(float4*)&hist[(size_t)b * 256 + lane * 4] = res;
    }
}

// ---------------- Kernel 2: backbone + per-target heads ----------------
// 16 rows per block, 256 threads. Measured-best (~32 us) b128 version.
__global__ __launch_bounds__(256) void backbone_kernel(
    const float* __restrict__ x_static,
    const float* __restrict__ W1, const float* __restrict__ b1,
    const float* __restrict__ g1, const float* __restrict__ be1,
    const float* __restrict__ m1, const float* __restrict__ v1,
    const float* __restrict__ W2, const float* __restrict__ b2,
    const float* __restrict__ g2, const float* __restrict__ be2,
    const float* __restrict__ m2, const float* __restrict__ v2,
    const float* __restrict__ Wh1, const float* __restrict__ bh1,
    const float* __restrict__ Wh2, const float* __restrict__ bh2,
    const float* __restrict__ hist, float* __restrict__ out)
{
    __shared__ float s_x[16 * 64];
    __shared__ float s_z1[16 * 256];
    __shared__ float s_z2[16 * 132];

    const int tid = threadIdx.x;
    const int row0 = blockIdx.x * 16;

    *(float4*)&s_x[tid * 4] = ld4(x_static + (size_t)row0 * 64 + tid * 4);
    __syncthreads();

    {
        const int col = tid;
        float acc[16];
        #pragma unroll
        for (int r = 0; r < 16; ++r) acc[r] = 0.f;
        for (int k4 = 0; k4 < 16; ++k4) {
            float w0 = W1[(k4 * 4 + 0) * 256 + col];
            float w1 = W1[(k4 * 4 + 1) * 256 + col];
            float w2 = W1[(k4 * 4 + 2) * 256 + col];
            float w3 = W1[(k4 * 4 + 3) * 256 + col];
            #pragma unroll
            for (int r = 0; r < 16; ++r) {
                float4 xv = *(float4*)&s_x[r * 64 + k4 * 4];
                acc[r] += xv.x * w0 + xv.y * w1 + xv.z * w2 + xv.w * w3;
            }
        }
        float sc = rsqrtf(v1[col] + 1e-5f) * g1[col];
        float off = b1[col] - m1[col];
        float bb = be1[col];
        #pragma unroll
        for (int r = 0; r < 16; ++r)
            s_z1[r * 256 + col] = fmaxf((acc[r] + off) * sc + bb, 0.f);
    }
    __syncthreads();

    {
        const int col = tid & 127;
        const int r0 = (tid >> 7) * 8;
        float acc[8];
        #pragma unroll
        for (int r = 0; r < 8; ++r) acc[r] = 0.f;
        for (int k4 = 0; k4 < 64; ++k4) {
            float w0 = W2[(k4 * 4 + 0) * 128 + col];
            float w1 = W2[(k4 * 4 + 1) * 128 + col];
            float w2 = W2[(k4 * 4 + 2) * 128 + col];
            float w3 = W2[(k4 * 4 + 3) * 128 + col];
            #pragma unroll
            for (int r = 0; r < 8; ++r) {
                float4 zv = *(float4*)&s_z1[(r0 + r) * 256 + k4 * 4];
                acc[r] += zv.x * w0 + zv.y * w1 + zv.z * w2 + zv.w * w3;
            }
        }
        float sc = rsqrtf(v2[col] + 1e-5f) * g2[col];
        float off = b2[col] - m2[col];
        float bb = be2[col];
        #pragma unroll
        for (int r = 0; r < 8; ++r)
            s_z2[(r0 + r) * 132 + col] = fmaxf((acc[r] + off) * sc + bb, 0.f);
    }
    __syncthreads();

    {
        const int p = tid >> 2;
        const int gl = tid & 3;
        const int row = p >> 2;
        const int tgt = p & 3;
        const int j0 = gl * 8;

        float acc[8];
        #pragma unroll
        for (int j = 0; j < 8; ++j) acc[j] = bh1[tgt * 32 + j0 + j];

        const float* w1p = Wh1 + (size_t)tgt * 192 * 32 + j0;
        for (int d4 = 0; d4 < 32; ++d4) {
            float4 zv = *(float4*)&s_z2[row * 132 + d4 * 4];
            #pragma unroll
            for (int c = 0; c < 4; ++c) {
                float v = (c == 0) ? zv.x : (c == 1) ? zv.y : (c == 2) ? zv.z : zv.w;
                float4 a = ld4(w1p + (d4 * 4 + c) * 32);
                float4 bq = ld4(w1p + (d4 * 4 + c) * 32 + 4);
                acc[0] += v * a.x;  acc[1] += v * a.y;  acc[2] += v * a.z;  acc[3] += v * a.w;
                acc[4] += v * bq.x; acc[5] += v * bq.y; acc[6] += v * bq.z; acc[7] += v * bq.w;
            }
        }
        const float* hp = hist + (size_t)(row0 + row) * 256 + tgt * 64;
        const float* w1q = w1p + 128 * 32;
        for (int d4 = 0; d4 < 16; ++d4) {
            float4 hv = ld4(hp + d4 * 4);
            #pragma unroll
            for (int c = 0; c < 4; ++c) {
                float v = (c == 0) ? hv.x : (c == 1) ? hv.y : (c == 2) ? hv.z : hv.w;
                float4 a = ld4(w1q + (d4 * 4 + c) * 32);
                float4 bq = ld4(w1q + (d4 * 4 + c) * 32 + 4);
                acc[0] += v * a.x;  acc[1] += v * a.y;  acc[2] += v * a.z;  acc[3] += v * a.w;
                acc[4] += v * bq.x; acc[5] += v * bq.y; acc[6] += v * bq.z; acc[7] += v * bq.w;
            }
        }
        float ps = 0.f;
        #pragma unroll
        for (int j = 0; j < 8; ++j) ps += fmaxf(acc[j], 0.f) * Wh2[tgt * 32 + j0 + j];
        ps += __shfl_xor(ps, 1);
        ps += __shfl_xor(ps, 2);
        if (gl == 0) out[(size_t)(row0 + row) * 4 + tgt] = fmaxf(ps + bh2[tgt], 0.f);
    }
}

extern "C" void kernel_launch(void* const* d_in, const int* in_sizes, int n_in,
                              void* d_out, int out_size, void* d_ws, size_t ws_size,
                              hipStream_t stream) {
    const float* x_static = (const float*)d_in[0];
    const float* x_kicks  = (const float*)d_in[1];
    const float* W_ke     = (const float*)d_in[2];
    const float* b_ke     = (const float*)d_in[3];
    const float* q_inner  = (const float*)d_in[4];
    const float* W_ge     = (const float*)d_in[5];
    const float* b_ge     = (const float*)d_in[6];
    const float* pos_emb  = (const float*)d_in[7];
    const float* q_outer  = (const float*)d_in[8];
    const float* log_temp = (const float*)d_in[9];
    const float* ln_g     = (const float*)d_in[10];
    const float* ln_b     = (const float*)d_in[11];
    const float* W1       = (const float*)d_in[12];
    const float* b1       = (const float*)d_in[13];
    const float* g1       = (const float*)d_in[14];
    const float* be1      = (const float*)d_in[15];
    const float* m1       = (const float*)d_in[16];
    const float* v1       = (const float*)d_in[17];
    const float* W2       = (const float*)d_in[18];
    const float* b2       = (const float*)d_in[19];
    const float* g2       = (const float*)d_in[20];
    const float* be2      = (const float*)d_in[21];
    const float* m2       = (const float*)d_in[22];
    const float* v2       = (const float*)d_in[23];
    const float* Wh1      = (const float*)d_in[24];
    const float* bh1      = (const float*)d_in[25];
    const float* Wh2      = (const float*)d_in[26];
    const float* bh2      = (const float*)d_in[27];
    const int* outer_mask = (const int*)d_in[28];
    const int* inner_mask = (const int*)d_in[29];

    float* hist = (float*)d_ws;           // 16384 * 256 floats = 16.8 MB
    float* out  = (float*)d_out;

    hist_kernel<<<16384 / 4, 256, 0, stream>>>(
        x_kicks, W_ke, b_ke, q_inner, W_ge, b_ge, pos_emb, q_outer,
        log_temp, ln_g, ln_b, outer_mask, inner_mask, hist);

    backbone_kernel<<<16384 / 16, 256, 0, stream>>>(
        x_static, W1, b1, g1, be1, m1, v1, W2, b2, g2, be2, m2, v2,
        Wh1, bh1, Wh2, bh2, hist, out);
}

// Round 22
// 135.193 us; speedup vs baseline: 1.1573x; 1.0668x over previous
//
#include <hip/hip_runtime.h>
#include <math.h>

#define NEGM (-1e30f)

typedef __fp16 f16x4 __attribute__((ext_vector_type(4)));
typedef __fp16 f16x2 __attribute__((ext_vector_type(2)));
typedef float  f32x4 __attribute__((ext_vector_type(4)));

__device__ __forceinline__ float4 ld4(const float* p) { return *(const float4*)p; }
__device__ __forceinline__ void fma4(float4& a, float s, const float4 w) {
    a.x += s * w.x; a.y += s * w.y; a.z += s * w.z; a.w += s * w.w;
}

// ---------------- Kernel 1: nested-attention history path ----------------
// One wave per row (R18, best measured). Phase A: MFMA encode + MFMA pool,
// packed-f16 score butterfly (8 DS ops), incremental game/pos counters.
__global__ __launch_bounds__(64) void hist_kernel(
    const float* __restrict__ x_kicks,
    const float* __restrict__ W_ke, const float* __restrict__ b_ke,
    const float* __restrict__ q_inner,
    const float* __restrict__ W_ge, const float* __restrict__ b_ge,
    const float* __restrict__ pos_emb, const float* __restrict__ q_outer,
    const float* __restrict__ log_temp,
    const float* __restrict__ ln_g, const float* __restrict__ ln_b,
    const int* __restrict__ outer_mask, const int* __restrict__ inner_mask,
    float* __restrict__ hist)
{
    __shared__ float s_wge[512];     // W_ge [16][32]
    __shared__ float s_qout[256];    // q_outer [8][32]
    __shared__ float pg[17 * 20];    // per_game, stride 20
    __shared__ float enc[17 * 36];   // encoded, stride 36
    __shared__ float ao[136];        // outer scores -> weights
    __shared__ float s_S[20];        // per-game softmax denominators

    const int lane = threadIdx.x;    // 0..63
    const int b    = blockIdx.x;
    const int jcol = lane & 15;      // MFMA col / A-row sel
    const int g    = lane >> 4;      // k-group
    const int kb   = g * 4;          // k base

    // stage B-E weights
    *(float4*)&s_wge[lane * 4]       = ld4(W_ge + lane * 4);
    *(float4*)&s_wge[256 + lane * 4] = ld4(W_ge + 256 + lane * 4);
    *(float4*)&s_qout[lane * 4]      = ld4(q_outer + lane * 4);

    // ---- per-lane constant fragments ----
    f16x4 bw;                         // B_W[k=kb+jj][j=jcol]
    #pragma unroll
    for (int jj = 0; jj < 4; ++jj)
        bw[jj] = (__fp16)W_ke[(kb + jj) * 16 + jcol];
    const float bias = b_ke[jcol];
    const f32x4 cinit = {bias, bias, bias, bias};
    const float qv = q_inner[jcol] * 0.25f;   // fold DK^-0.5 into q

    const float* xb = x_kicks + (size_t)b * 204 * 16;
    const int*   mb = inner_mask + (size_t)b * 204;

    f32x4 PG   = {0.f, 0.f, 0.f, 0.f};
    f32x4 PG16 = {0.f, 0.f, 0.f, 0.f};
    float Sacc = 0.f, S16 = 0.f;

    // incremental game/pos counters for kick0 = 16t + 4g
    int g0 = (g == 3) ? 1 : 0;       // (4g)/12
    int p0 = (g == 3) ? 0 : 4 * g;   // (4g)%12

    // ---------- tiles 0..11 : games 0..15 ----------
    #pragma unroll
    for (int t = 0; t < 12; ++t) {
        float4 xv = ld4(xb + (16 * t + jcol) * 16 + kb);
        int4 mv = *(const int4*)(mb + 16 * t + 4 * g);

        f16x2 xlo = __builtin_amdgcn_cvt_pkrtz(xv.x, xv.y);
        f16x2 xhi = __builtin_amdgcn_cvt_pkrtz(xv.z, xv.w);
        f16x4 ax; ax[0]=xlo[0]; ax[1]=xlo[1]; ax[2]=xhi[0]; ax[3]=xhi[1];

        f32x4 D1 = __builtin_amdgcn_mfma_f32_16x16x16f16(ax, bw, cinit, 0, 0, 0);
        #pragma unroll
        for (int jj = 0; jj < 4; ++jj) D1[jj] = fmaxf(D1[jj], 0.f);

        // scores: packed-f16 butterfly over 16 lanes (8 DS ops)
        f16x2 pA = __builtin_amdgcn_cvt_pkrtz(D1[0] * qv, D1[1] * qv);
        f16x2 pB = __builtin_amdgcn_cvt_pkrtz(D1[2] * qv, D1[3] * qv);
        #pragma unroll
        for (int o = 1; o < 16; o <<= 1) {
            int ia = __shfl_xor(__builtin_bit_cast(int, pA), o);
            int ib = __shfl_xor(__builtin_bit_cast(int, pB), o);
            pA = pA + __builtin_bit_cast(f16x2, ia);
            pB = pB + __builtin_bit_cast(f16x2, ib);
        }
        float s0 = (float)pA[0], s1 = (float)pA[1];
        float s2 = (float)pB[0], s3 = (float)pB[1];

        // pooling weights: game index via incremental counters
        f16x4 aw;
        #pragma unroll
        for (int jj = 0; jj < 4; ++jj) {
            int mk = (jj==0)?mv.x:(jj==1)?mv.y:(jj==2)?mv.z:mv.w;
            float sv = (jj==0)?s0:(jj==1)?s1:(jj==2)?s2:s3;
            float e = mk ? __expf(sv) : 0.f;       // scores tiny: no max-sub
            int game_jj = g0 + ((p0 + jj) >= 12 ? 1 : 0);
            float w = (game_jj == jcol) ? e : 0.f;
            aw[jj] = (__fp16)w;
            Sacc += w;
        }
        // advance counters: kick0 += 16
        g0 += 1; p0 += 4;
        if (p0 >= 12) { p0 -= 12; g0 += 1; }

        f16x2 elo = __builtin_amdgcn_cvt_pkrtz(D1[0], D1[1]);
        f16x2 ehi = __builtin_amdgcn_cvt_pkrtz(D1[2], D1[3]);
        f16x4 be; be[0]=elo[0]; be[1]=elo[1]; be[2]=ehi[0]; be[3]=ehi[1];

        PG = __builtin_amdgcn_mfma_f32_16x16x16f16(aw, be, PG, 0, 0, 0);
    }

    // ---------- tile 12 : game 16 (kicks 192..203) ----------
    {
        int kidx = 192 + jcol;
        int kc = (kidx < 204) ? kidx : 203;
        float4 xv = ld4(xb + kc * 16 + kb);
        int km = 192 + 4 * g;
        int kmc = (km <= 200) ? km : 200;
        int4 mv = *(const int4*)(mb + kmc);

        f16x2 xlo = __builtin_amdgcn_cvt_pkrtz(xv.x, xv.y);
        f16x2 xhi = __builtin_amdgcn_cvt_pkrtz(xv.z, xv.w);
        f16x4 ax; ax[0]=xlo[0]; ax[1]=xlo[1]; ax[2]=xhi[0]; ax[3]=xhi[1];

        f32x4 D1 = __builtin_amdgcn_mfma_f32_16x16x16f16(ax, bw, cinit, 0, 0, 0);
        #pragma unroll
        for (int jj = 0; jj < 4; ++jj) D1[jj] = fmaxf(D1[jj], 0.f);

        f16x2 pA = __builtin_amdgcn_cvt_pkrtz(D1[0] * qv, D1[1] * qv);
        f16x2 pB = __builtin_amdgcn_cvt_pkrtz(D1[2] * qv, D1[3] * qv);
        #pragma unroll
        for (int o = 1; o < 16; o <<= 1) {
            int ia = __shfl_xor(__builtin_bit_cast(int, pA), o);
            int ib = __shfl_xor(__builtin_bit_cast(int, pB), o);
            pA = pA + __builtin_bit_cast(f16x2, ia);
            pB = pB + __builtin_bit_cast(f16x2, ib);
        }
        float s0 = (float)pA[0], s1 = (float)pA[1];
        float s2 = (float)pB[0], s3 = (float)pB[1];

        f16x4 aw2;
        #pragma unroll
        for (int jj = 0; jj < 4; ++jj) {
            int pos = 4 * g + jj;
            int mk = (jj==0)?mv.x:(jj==1)?mv.y:(jj==2)?mv.z:mv.w;
            float sv = (jj==0)?s0:(jj==1)?s1:(jj==2)?s2:s3;
            bool valid = (pos < 12) && mk;
            float e = valid ? __expf(sv) : 0.f;
            float w = (jcol == 0) ? e : 0.f;       // single output row 0
            aw2[jj] = (__fp16)w;
            S16 += w;
        }

        f16x2 elo = __builtin_amdgcn_cvt_pkrtz(D1[0], D1[1]);
        f16x2 ehi = __builtin_amdgcn_cvt_pkrtz(D1[2], D1[3]);
        f16x4 be; be[0]=elo[0]; be[1]=elo[1]; be[2]=ehi[0]; be[3]=ehi[1];

        PG16 = __builtin_amdgcn_mfma_f32_16x16x16f16(aw2, be, PG16, 0, 0, 0);
    }

    // ---------- softmax denominators & per_game write ----------
    Sacc += __shfl_xor(Sacc, 16);
    Sacc += __shfl_xor(Sacc, 32);        // all lanes: S[game=jcol]
    S16 += __shfl_xor(S16, 16);
    S16 += __shfl_xor(S16, 32);          // lanes with jcol==0 hold S16

    if (lane < 16) s_S[lane] = Sacc;     // S[0..15]
    if (lane == 0) s_S[16] = S16;
    __syncthreads();

    #pragma unroll
    for (int jj = 0; jj < 4; ++jj) {
        int game = kb + jj;              // PG row = (lane>>4)*4+jj
        pg[game * 20 + jcol] = PG[jj] * (1.f / s_S[game]);
    }
    if (lane < 16) pg[16 * 20 + lane] = PG16[0] * (1.f / s_S[16]);
    __syncthreads();

    // ---------- Phase B: game encoder + pos emb -> enc[17][32] ----------
    for (int t = lane; t < 136; t += 64) {
        const int gg = t >> 3, dq = t & 7;
        float4 acc = ld4(b_ge + dq * 4);
        #pragma unroll
        for (int i = 0; i < 16; ++i) {
            float pv = pg[gg * 20 + i];
            fma4(acc, pv, *(float4*)&s_wge[i * 32 + dq * 4]);
        }
        float4 pe = ld4(pos_emb + gg * 32 + dq * 4);
        acc.x = fmaxf(acc.x, 0.f) + pe.x; acc.y = fmaxf(acc.y, 0.f) + pe.y;
        acc.z = fmaxf(acc.z, 0.f) + pe.z; acc.w = fmaxf(acc.w, 0.f) + pe.w;
        *(float4*)&enc[gg * 36 + dq * 4] = acc;
    }
    __syncthreads();

    // ---------- Phase C: outer attention scores ao[8][17] ----------
    for (int t = lane; t < 136; t += 64) {
        const int q = t / 17, gg = t - q * 17;
        float4 acc = {0.f, 0.f, 0.f, 0.f};
        #pragma unroll
        for (int i4 = 0; i4 < 8; ++i4) {
            float4 ev = *(float4*)&enc[gg * 36 + i4 * 4];
            float4 qvv = *(float4*)&s_qout[q * 32 + i4 * 4];
            acc.x += ev.x * qvv.x; acc.y += ev.y * qvv.y;
            acc.z += ev.z * qvv.z; acc.w += ev.w * qvv.w;
        }
        float sv = (acc.x + acc.y) + (acc.z + acc.w);
        sv *= 0.17677669529663687f * __expf(-log_temp[q >> 1]);
        ao[t] = outer_mask[b * 17 + gg] ? sv : NEGM;
    }
    __syncthreads();

    // ---------- Phase D: outer softmax (8 lanes per query) ----------
    {
        const int q = lane >> 3, j = lane & 7;
        float s0 = ao[q * 17 + j];
        float s1 = ao[q * 17 + j + 8];
        float s2 = (j == 0) ? ao[q * 17 + 16] : NEGM;
        float mx = fmaxf(fmaxf(s0, s1), s2);
        mx = fmaxf(mx, __shfl_xor(mx, 1));
        mx = fmaxf(mx, __shfl_xor(mx, 2));
        mx = fmaxf(mx, __shfl_xor(mx, 4));
        float e0 = __expf(s0 - mx), e1 = __expf(s1 - mx);
        float e2 = (j == 0) ? __expf(s2 - mx) : 0.f;
        float ssum = e0 + e1 + e2;
        ssum += __shfl_xor(ssum, 1);
        ssum += __shfl_xor(ssum, 2);
        ssum += __shfl_xor(ssum, 4);
        float inv = 1.f / ssum;
        ao[q * 17 + j] = e0 * inv;
        ao[q * 17 + j + 8] = e1 * inv;
        if (j == 0) ao[q * 17 + 16] = e2 * inv;
    }
    __syncthreads();

    // ---------- Phase E: pooled + per-target LayerNorm ----------
    {
        const int q = lane >> 3, dq = lane & 7;
        float4 acc = {0.f, 0.f, 0.f, 0.f};
        #pragma unroll
        for (int gg = 0; gg < 17; ++gg) {
            float w = ao[q * 17 + gg];
            fma4(acc, w, *(float4*)&enc[gg * 36 + dq * 4]);
        }
        float sv = (acc.x + acc.y) + (acc.z + acc.w);
        sv += __shfl_xor(sv, 1); sv += __shfl_xor(sv, 2);
        sv += __shfl_xor(sv, 4); sv += __shfl_xor(sv, 8);
        float mu = sv * 0.015625f;
        float4 d;
        d.x = acc.x - mu; d.y = acc.y - mu; d.z = acc.z - mu; d.w = acc.w - mu;
        float v = (d.x * d.x + d.y * d.y) + (d.z * d.z + d.w * d.w);
        v += __shfl_xor(v, 1); v += __shfl_xor(v, 2);
        v += __shfl_xor(v, 4); v += __shfl_xor(v, 8);
        float rs = rsqrtf(v * 0.015625f + 1e-5f);
        float4 gam = ld4(ln_g + lane * 4);
        float4 bet = ld4(ln_b + lane * 4);
        float4 res;
        res.x = d.x * rs * gam.x + bet.x; res.y = d.y * rs * gam.y + bet.y;
        res.z = d.z * rs * gam.z + bet.z; res.w = d.w * rs * gam.w + bet.w;
        *(float4*)&hist[(size_t)b * 256 + lane * 4] = res;
    }
}

// ---------------- Kernel 2: backbone + per-target heads ----------------
// 16 rows per block, 256 threads. Measured-best (~32 us) b128 version.
__global__ __launch_bounds__(256) void backbone_kernel(
    const float* __restrict__ x_static,
    const float* __restrict__ W1, const float* __restrict__ b1,
    const float* __restrict__ g1, const float* __restrict__ be1,
    const float* __restrict__ m1, const float* __restrict__ v1,
    const float* __restrict__ W2, const float* __restrict__ b2,
    const float* __restrict__ g2, const float* __restrict__ be2,
    const float* __restrict__ m2, const float* __restrict__ v2,
    const float* __restrict__ Wh1, const float* __restrict__ bh1,
    const float* __restrict__ Wh2, const float* __restrict__ bh2,
    const float* __restrict__ hist, float* __restrict__ out)
{
    __shared__ float s_x[16 * 64];
    __shared__ float s_z1[16 * 256];
    __shared__ float s_z2[16 * 132];

    const int tid = threadIdx.x;
    const int row0 = blockIdx.x * 16;

    *(float4*)&s_x[tid * 4] = ld4(x_static + (size_t)row0 * 64 + tid * 4);
    __syncthreads();

    {
        const int col = tid;
        float acc[16];
        #pragma unroll
        for (int r = 0; r < 16; ++r) acc[r] = 0.f;
        for (int k4 = 0; k4 < 16; ++k4) {
            float w0 = W1[(k4 * 4 + 0) * 256 + col];
            float w1 = W1[(k4 * 4 + 1) * 256 + col];
            float w2 = W1[(k4 * 4 + 2) * 256 + col];
            float w3 = W1[(k4 * 4 + 3) * 256 + col];
            #pragma unroll
            for (int r = 0; r < 16; ++r) {
                float4 xv = *(float4*)&s_x[r * 64 + k4 * 4];
                acc[r] += xv.x * w0 + xv.y * w1 + xv.z * w2 + xv.w * w3;
            }
        }
        float sc = rsqrtf(v1[col] + 1e-5f) * g1[col];
        float off = b1[col] - m1[col];
        float bb = be1[col];
        #pragma unroll
        for (int r = 0; r < 16; ++r)
            s_z1[r * 256 + col] = fmaxf((acc[r] + off) * sc + bb, 0.f);
    }
    __syncthreads();

    {
        const int col = tid & 127;
        const int r0 = (tid >> 7) * 8;
        float acc[8];
        #pragma unroll
        for (int r = 0; r < 8; ++r) acc[r] = 0.f;
        for (int k4 = 0; k4 < 64; ++k4) {
            float w0 = W2[(k4 * 4 + 0) * 128 + col];
            float w1 = W2[(k4 * 4 + 1) * 128 + col];
            float w2 = W2[(k4 * 4 + 2) * 128 + col];
            float w3 = W2[(k4 * 4 + 3) * 128 + col];
            #pragma unroll
            for (int r = 0; r < 8; ++r) {
                float4 zv = *(float4*)&s_z1[(r0 + r) * 256 + k4 * 4];
                acc[r] += zv.x * w0 + zv.y * w1 + zv.z * w2 + zv.w * w3;
            }
        }
        float sc = rsqrtf(v2[col] + 1e-5f) * g2[col];
        float off = b2[col] - m2[col];
        float bb = be2[col];
        #pragma unroll
        for (int r = 0; r < 8; ++r)
            s_z2[(r0 + r) * 132 + col] = fmaxf((acc[r] + off) * sc + bb, 0.f);
    }
    __syncthreads();

    {
        const int p = tid >> 2;
        const int gl = tid & 3;
        const int row = p >> 2;
        const int tgt = p & 3;
        const int j0 = gl * 8;

        float acc[8];
        #pragma unroll
        for (int j = 0; j < 8; ++j) acc[j] = bh1[tgt * 32 + j0 + j];

        const float* w1p = Wh1 + (size_t)tgt * 192 * 32 + j0;
        for (int d4 = 0; d4 < 32; ++d4) {
            float4 zv = *(float4*)&s_z2[row * 132 + d4 * 4];
            #pragma unroll
            for (int c = 0; c < 4; ++c) {
                float v = (c == 0) ? zv.x : (c == 1) ? zv.y : (c == 2) ? zv.z : zv.w;
                float4 a = ld4(w1p + (d4 * 4 + c) * 32);
                float4 bq = ld4(w1p + (d4 * 4 + c) * 32 + 4);
                acc[0] += v * a.x;  acc[1] += v * a.y;  acc[2] += v * a.z;  acc[3] += v * a.w;
                acc[4] += v * bq.x; acc[5] += v * bq.y; acc[6] += v * bq.z; acc[7] += v * bq.w;
            }
        }
        const float* hp = hist + (size_t)(row0 + row) * 256 + tgt * 64;
        const float* w1q = w1p + 128 * 32;
        for (int d4 = 0; d4 < 16; ++d4) {
            float4 hv = ld4(hp + d4 * 4);
            #pragma unroll
            for (int c = 0; c < 4; ++c) {
                float v = (c == 0) ? hv.x : (c == 1) ? hv.y : (c == 2) ? hv.z : hv.w;
                float4 a = ld4(w1q + (d4 * 4 + c) * 32);
                float4 bq = ld4(w1q + (d4 * 4 + c) * 32 + 4);
                acc[0] += v * a.x;  acc[1] += v * a.y;  acc[2] += v * a.z;  acc[3] += v * a.w;
                acc[4] += v * bq.x; acc[5] += v * bq.y; acc[6] += v * bq.z; acc[7] += v * bq.w;
            }
        }
        float ps = 0.f;
        #pragma unroll
        for (int j = 0; j < 8; ++j) ps += fmaxf(acc[j], 0.f) * Wh2[tgt * 32 + j0 + j];
        ps += __shfl_xor(ps, 1);
        ps += __shfl_xor(ps, 2);
        if (gl == 0) out[(size_t)(row0 + row) * 4 + tgt] = fmaxf(ps + bh2[tgt], 0.f);
    }
}

extern "C" void kernel_launch(void* const* d_in, const int* in_sizes, int n_in,
                              void* d_out, int out_size, void* d_ws, size_t ws_size,
                              hipStream_t stream) {
    const float* x_static = (const float*)d_in[0];
    const float* x_kicks  = (const float*)d_in[1];
    const float* W_ke     = (const float*)d_in[2];
    const float* b_ke     = (const float*)d_in[3];
    const float* q_inner  = (const float*)d_in[4];
    const float* W_ge     = (const float*)d_in[5];
    const float* b_ge     = (const float*)d_in[6];
    const float* pos_emb  = (const float*)d_in[7];
    const float* q_outer  = (const float*)d_in[8];
    const float* log_temp = (const float*)d_in[9];
    const float* ln_g     = (const float*)d_in[10];
    const float* ln_b     = (const float*)d_in[11];
    const float* W1       = (const float*)d_in[12];
    const float* b1       = (const float*)d_in[13];
    const float* g1       = (const float*)d_in[14];
    const float* be1      = (const float*)d_in[15];
    const float* m1       = (const float*)d_in[16];
    const float* v1       = (const float*)d_in[17];
    const float* W2       = (const float*)d_in[18];
    const float* b2       = (const float*)d_in[19];
    const float* g2       = (const float*)d_in[20];
    const float* be2      = (const float*)d_in[21];
    const float* m2       = (const float*)d_in[22];
    const float* v2       = (const float*)d_in[23];
    const float* Wh1      = (const float*)d_in[24];
    const float* bh1      = (const float*)d_in[25];
    const float* Wh2      = (const float*)d_in[26];
    const float* bh2      = (const float*)d_in[27];
    const int* outer_mask = (const int*)d_in[28];
    const int* inner_mask = (const int*)d_in[29];

    float* hist = (float*)d_ws;           // 16384 * 256 floats = 16.8 MB
    float* out  = (float*)d_out;

    hist_kernel<<<16384, 64, 0, stream>>>(
        x_kicks, W_ke, b_ke, q_inner, W_ge, b_ge, pos_emb, q_outer,
        log_temp, ln_g, ln_b, outer_mask, inner_mask, hist);

    backbone_kernel<<<16384 / 16, 256, 0, stream>>>(
        x_static, W1, b1, g1, be1, m1, v1, W2, b2, g2, be2, m2, v2,
        Wh1, bh1, Wh2, bh2, hist, out);
}